// Round 1
// baseline (143.793 us; speedup 1.0000x reference)
//
#include <hip/hip_runtime.h>
#include <math.h>

#ifndef __has_builtin
#define __has_builtin(x) 0
#endif

#define H1N 10
#define H2N 6
#define NTHREADS 256
#define NWAVES (NTHREADS / 64)

__device__ __forceinline__ float frcpf(float x) {
#if __has_builtin(__builtin_amdgcn_rcpf)
    return __builtin_amdgcn_rcpf(x);
#else
    return 1.0f / x;
#endif
}

// tanh(z) = 1 - 2/(exp(2z)+1); hw v_exp_f32 + v_rcp_f32, ~1e-7 abs err.
// Overflow-safe: z>>0 -> e=inf -> 1; z<<0 -> e=0 -> -1.
__device__ __forceinline__ float fast_tanh(float z) {
    float e = __expf(2.0f * z);
    return 1.0f - 2.0f * frcpf(e + 1.0f);
}

// Forward value and exact 2nd derivative of the 1->10->6->1 tanh MLP at scalar x.
__device__ __forceinline__ void eval_net(
    float x,
    const float* __restrict__ W1, const float* __restrict__ B1,
    const float* __restrict__ W2, const float* __restrict__ B2,
    const float* __restrict__ W3, float b3,
    float& out, float& g2)
{
    float z2[H2N], dz2[H2N], ez2[H2N];
#pragma unroll
    for (int k = 0; k < H2N; ++k) { z2[k] = B2[k]; dz2[k] = 0.f; ez2[k] = 0.f; }
#pragma unroll
    for (int j = 0; j < H1N; ++j) {
        float w = W1[j];
        float z = fmaf(x, w, B1[j]);
        float t = fast_tanh(z);
        float s = fmaf(-t, t, 1.0f);       // sech^2
        float d = s * w;                    // h1'
        float e = -2.0f * t * d * w;        // h1'' = -2 t s w^2
#pragma unroll
        for (int k = 0; k < H2N; ++k) {
            float w2 = W2[j * H2N + k];
            z2[k]  = fmaf(t, w2, z2[k]);
            dz2[k] = fmaf(d, w2, dz2[k]);
            ez2[k] = fmaf(e, w2, ez2[k]);
        }
    }
    float o = b3, g = 0.f;
#pragma unroll
    for (int k = 0; k < H2N; ++k) {
        float t = fast_tanh(z2[k]);
        float s = fmaf(-t, t, 1.0f);
        // h2'' = s*z2'' - 2 t s (z2')^2
        float hpp = fmaf(s, ez2[k], -2.0f * t * s * dz2[k] * dz2[k]);
        o = fmaf(t, W3[k], o);
        g = fmaf(hpp, W3[k], g);
    }
    out = o;
    g2 = g;
}

// Pass 1: compute raw out -> d_out[0..N), accumulate sum(out), sum(out^2), sum(g2^2).
__global__ __launch_bounds__(NTHREADS) void pass1(
    const float4* __restrict__ x4,
    const float* __restrict__ W1, const float* __restrict__ B1,
    const float* __restrict__ W2, const float* __restrict__ B2,
    const float* __restrict__ W3, const float* __restrict__ B3,
    float4* __restrict__ out4,
    double* __restrict__ acc,
    int n4)
{
    const float b3 = B3[0];
    float so = 0.f, so2 = 0.f, sg = 0.f;
    const int stride = gridDim.x * blockDim.x;
    for (int i = blockIdx.x * blockDim.x + threadIdx.x; i < n4; i += stride) {
        float4 v = x4[i];
        float4 o;
        float oo, gg;
        eval_net(v.x, W1, B1, W2, B2, W3, b3, oo, gg);
        o.x = oo; so += oo; so2 = fmaf(oo, oo, so2); sg = fmaf(gg, gg, sg);
        eval_net(v.y, W1, B1, W2, B2, W3, b3, oo, gg);
        o.y = oo; so += oo; so2 = fmaf(oo, oo, so2); sg = fmaf(gg, gg, sg);
        eval_net(v.z, W1, B1, W2, B2, W3, b3, oo, gg);
        o.z = oo; so += oo; so2 = fmaf(oo, oo, so2); sg = fmaf(gg, gg, sg);
        eval_net(v.w, W1, B1, W2, B2, W3, b3, oo, gg);
        o.w = oo; so += oo; so2 = fmaf(oo, oo, so2); sg = fmaf(gg, gg, sg);
        out4[i] = o;
    }

    // wave (64-lane) shuffle reduce
    for (int off = 32; off > 0; off >>= 1) {
        so  += __shfl_down(so,  off);
        so2 += __shfl_down(so2, off);
        sg  += __shfl_down(sg,  off);
    }
    __shared__ float r0[NWAVES], r1[NWAVES], r2[NWAVES];
    const int wave = threadIdx.x >> 6;
    const int lane = threadIdx.x & 63;
    if (lane == 0) { r0[wave] = so; r1[wave] = so2; r2[wave] = sg; }
    __syncthreads();
    if (threadIdx.x == 0) {
        float a0 = 0.f, a1 = 0.f, a2 = 0.f;
#pragma unroll
        for (int wv = 0; wv < NWAVES; ++wv) { a0 += r0[wv]; a1 += r1[wv]; a2 += r2[wv]; }
        atomicAdd(&acc[0], (double)a0);
        atomicAdd(&acc[1], (double)a1);
        atomicAdd(&acc[2], (double)a2);
    }
}

// Pass 2: normalize d_out in place, write penalty scalar at d_out[N].
__global__ __launch_bounds__(NTHREADS) void pass2(
    float* __restrict__ out,
    const double* __restrict__ acc,
    int n4, int n)
{
    const double dn   = (double)n;
    const double mean = acc[0] / dn;
    double var = acc[1] / dn - mean * mean;
    if (var < 0.0) var = 0.0;
    double sd = sqrt(var);
    const double norm = sd > 1e-10 ? sd : 1e-10;
    const float  inv  = (float)(1.0 / norm);
    const float  mu   = (float)mean;

    float4* o4 = (float4*)out;
    const int stride = gridDim.x * blockDim.x;
    for (int i = blockIdx.x * blockDim.x + threadIdx.x; i < n4; i += stride) {
        float4 v = o4[i];
        v.x = (v.x - mu) * inv;
        v.y = (v.y - mu) * inv;
        v.z = (v.z - mu) * inv;
        v.w = (v.w - mu) * inv;
        o4[i] = v;
    }
    if (blockIdx.x == 0 && threadIdx.x == 0) {
        out[n] = (float)((acc[2] / dn) / norm);
    }
}

extern "C" void kernel_launch(void* const* d_in, const int* in_sizes, int n_in,
                              void* d_out, int out_size, void* d_ws, size_t ws_size,
                              hipStream_t stream) {
    const float* x  = (const float*)d_in[0];
    const float* W1 = (const float*)d_in[1];
    const float* B1 = (const float*)d_in[2];
    const float* W2 = (const float*)d_in[3];
    const float* B2 = (const float*)d_in[4];
    const float* W3 = (const float*)d_in[5];
    const float* B3 = (const float*)d_in[6];

    const int n  = in_sizes[0];   // 4,194,304 (divisible by 4)
    const int n4 = n >> 2;

    float*  out = (float*)d_out;
    double* acc = (double*)d_ws;  // 3 doubles; ws is re-poisoned each call

    hipMemsetAsync(acc, 0, 3 * sizeof(double), stream);

    // 1024 blocks -> 16 samples/thread; compute-bound VALU kernel.
    pass1<<<1024, NTHREADS, 0, stream>>>(
        (const float4*)x, W1, B1, W2, B2, W3, B3,
        (float4*)out, acc, n4);

    // memory-bound in-place normalize
    pass2<<<2048, NTHREADS, 0, stream>>>(out, acc, n4, n);
}